// Round 12
// baseline (49.087 us; speedup 1.0000x reference)
//
#include <hip/hip_runtime.h>

// Gaussian-splat heatmap as a per-image MFMA GEMM — R11 + NONTEMPORAL stores
// (single-variable change vs R11, 24.26us).
//   heat[y][x] = sum_p Rmat[y][p] * CmatT[x][p]   (M=N=200 padded to 224, K=64)
//   Rmat[y][p]  = k1n[y-ys_p] if 0<=y-ys_p<ky_p else 0  (top-left-slice quirk)
//   CmatT[x][p] = k1n[x-xs_p] if 0<=x-xs_p<kx_p else 0
// bf16 LDS rows of 128 B, XOR-swizzled byte ^= ((row&7)<<4) (G4/T2).
// mfma_f32_32x32x16_bf16; A-frag: lane l -> row l&31, k=8*(l>>5)+j;
// C/D: col=lane&31, row=(reg&3)+8*(reg>>2)+4*(lane>>5)   [m74/m101]
//
// Store-path theory: output rows are 800 B (not 128-aligned), so every 128 B
// store segment straddles two cache lines; L2 fetches each line on first
// partial write (read-for-ownership). R5's counters showed exactly this
// signature (FETCH_SIZE ~8 MB for 0.26 MB of input). Nontemporal stores set
// the `nt` no-allocate flag -> no RFO fetch, no L2 pollution. Values and
// order unchanged -> bit-identical output to R11.

#define NT 64
#define TDIM 224
#define NTL 7
#define BLK 512

typedef short bf16x8 __attribute__((ext_vector_type(8)));
typedef float f32x16 __attribute__((ext_vector_type(16)));

// f32 -> bf16 round-to-nearest-even
static __device__ inline unsigned short f2bf(float f) {
    unsigned int u = __float_as_uint(f);
    u = (u + 0x7FFFu + ((u >> 16) & 1u)) >> 16;
    return (unsigned short)u;
}

struct __align__(16) SMem {
    unsigned short Rm[TDIM][64];   // 28,672 B, swizzled (rows = y)
    unsigned short Cm[TDIM][64];   // 28,672 B, swizzled (rows = x)  (contiguous with Rm)
    float k1f[37];                 // f32 normalized 1-D gaussian
    float wmax[NTL];
};

__global__ __launch_bounds__(BLK) void heatmap_kernel(const float* __restrict__ x_t,
                                                      float* __restrict__ out) {
    __shared__ SMem s;
    const int tid  = threadIdx.x;
    const int lane = tid & 63;
    const int wv   = tid >> 6;      // 0..7 (wave 7 idles in compute, helps build)
    const int b    = blockIdx.x;

    // --- (1) zero-fill Rm+Cm with b128 writes: 57,344 B = 3584 x 16 B ---
    {
        uint4 z = {0u, 0u, 0u, 0u};
        uint4* base = (uint4*)s.Rm;
        #pragma unroll
        for (int i = 0; i < 7; ++i) base[tid + BLK * i] = z;
    }
    // --- (2) f32 normalized 1-D gaussian table ---
    if (tid < 37) {
        float sum = 0.0f, mine = 0.0f;
        #pragma unroll
        for (int i = 0; i < 37; ++i) {
            float r = (float)(i - 18);
            float v = expf(-(r * r) * (1.0f / 18.0f));   // sigma=3 -> 2*sigma^2=18
            sum += v;
            if (i == tid) mine = v;
        }
        s.k1f[tid] = mine / sum;
    }
    __syncthreads();

    // --- (3) sparse build: task = (point p, matrix R/C), 4 threads x 9 rows ---
    {
        const int p   = (tid >> 2) & 63;    // point
        const int isC = tid >> 8;           // 0: Rm (rows=y), 1: Cm (rows=x)
        const int j   = tid & 3;            // 9-row slice
        const float2 xy = *(const float2*)(x_t + (size_t)b * 128 + 2 * p);
        // replicates reference exactly
        const bool valid = (xy.x == xy.x) && (xy.y == xy.y);
        const int xp = (int)(xy.x * 2.0f);            // trunc == astype(int32), x>=0
        const int yp = 200 - (int)(xy.y * 2.0f);
        const int xs = min(max(xp - 18, 0), 164);
        const int ys = min(max(yp - 18, 0), 164);
        const int kx = valid ? (min(max(xp + 18, 0), 200) - xs) : 0;   // <= 36
        const int ky = valid ? (min(max(yp + 18, 0), 200) - ys) : 0;
        const int start = isC ? xs : ys;
        const int len   = isC ? kx : ky;
        char* dst = isC ? (char*)s.Cm : (char*)s.Rm;
        #pragma unroll
        for (int i = 0; i < 9; ++i) {
            const int rel = j * 9 + i;                // 0..35
            if (rel < len) {
                const int row = start + rel;          // <= 199
                const int off = (2 * p) ^ ((row & 7) << 4);
                *(unsigned short*)(dst + row * 128 + off) = f2bf(s.k1f[rel]);
            }
        }
    }
    __syncthreads();

    const int swl = (lane & 7) << 4;    // swizzle term (rows = t*32+(lane&31))

    // --- A fragments for this wave's y-tile ---
    bf16x8 A[4];
    if (wv < NTL) {
        const char* ab = (const char*)s.Rm + (wv * 32 + (lane & 31)) * 128;
        #pragma unroll
        for (int m = 0; m < 4; ++m)
            A[m] = *(const bf16x8*)(ab + ((16 * (2 * m + (lane >> 5))) ^ swl));
    }

    // --- pass 1: max ---
    float gmax = 0.0f;
    if (wv < NTL) {
        for (int tx = 0; tx < NTL; ++tx) {
            const char* bb = (const char*)s.Cm + (tx * 32 + (lane & 31)) * 128;
            f32x16 acc;
            #pragma unroll
            for (int r = 0; r < 16; ++r) acc[r] = 0.0f;
            #pragma unroll
            for (int m = 0; m < 4; ++m) {
                bf16x8 B = *(const bf16x8*)(bb + ((16 * (2 * m + (lane >> 5))) ^ swl));
                acc = __builtin_amdgcn_mfma_f32_32x32x16_bf16(A[m], B, acc, 0, 0, 0);
            }
            #pragma unroll
            for (int r = 0; r < 16; ++r) gmax = fmaxf(gmax, acc[r]);
        }
    }
    #pragma unroll
    for (int off = 32; off > 0; off >>= 1) gmax = fmaxf(gmax, __shfl_xor(gmax, off));
    if (wv < NTL && lane == 0) s.wmax[wv] = gmax;
    __syncthreads();
    float mm = s.wmax[0];
    #pragma unroll
    for (int w = 1; w < NTL; ++w) mm = fmaxf(mm, s.wmax[w]);
    const float scale = 1.0f / (mm + 1e-10f);

    // --- pass 2: recompute, normalize, nontemporal scattered-dword stores ---
    if (wv < NTL) {
        float* ob = out + (size_t)b * (200 * 200);
        const int colbase = lane & 31;
        const int rowoff  = wv * 32 + 4 * (lane >> 5);
        for (int tx = 0; tx < NTL; ++tx) {
            const char* bb = (const char*)s.Cm + (tx * 32 + (lane & 31)) * 128;
            f32x16 acc;
            #pragma unroll
            for (int r = 0; r < 16; ++r) acc[r] = 0.0f;
            #pragma unroll
            for (int m = 0; m < 4; ++m) {
                bf16x8 B = *(const bf16x8*)(bb + ((16 * (2 * m + (lane >> 5))) ^ swl));
                acc = __builtin_amdgcn_mfma_f32_32x32x16_bf16(A[m], B, acc, 0, 0, 0);
            }
            const int gcol = tx * 32 + colbase;
            #pragma unroll
            for (int r = 0; r < 16; ++r) {
                int grow = rowoff + (r & 3) + 8 * (r >> 2);
                if (grow < 200 && gcol < 200)
                    __builtin_nontemporal_store(acc[r] * scale,
                                                ob + (size_t)grow * 200 + gcol);
            }
        }
    }
}

extern "C" void kernel_launch(void* const* d_in, const int* in_sizes, int n_in,
                              void* d_out, int out_size, void* d_ws, size_t ws_size,
                              hipStream_t stream) {
    const float* x_t = (const float*)d_in[0];
    float* out = (float*)d_out;
    const int B = in_sizes[0] / (NT * 2);   // 512
    heatmap_kernel<<<B, BLK, 0, stream>>>(x_t, out);
}

// Round 13
// 34.475 us; speedup vs baseline: 1.4238x; 1.4238x over previous
//
#include <hip/hip_runtime.h>

// Gaussian-splat heatmap as a per-image MFMA GEMM.
//   heat[y][x] = sum_p Rmat[y][p] * CmatT[x][p]   (M=N=200 padded to 224, K=64)
//   Rmat[y][p]  = k1n[y-ys_p] if 0<=y-ys_p<ky_p else 0  (top-left-slice quirk)
//   CmatT[x][p] = k1n[x-xs_p] if 0<=x-xs_p<kx_p else 0
// bf16 LDS rows of 128 B, XOR-swizzled byte ^= ((row&7)<<4) (G4/T2).
//
// R13 = R11 (24.26us) with ONLY pass 2 changed (and R12's nt reverted — nt
// cost 2x by killing L2 write aggregation):
//   Pass 2 now uses mfma_f32_16x16x32_bf16: each wave computes a 16-row strip
//   across all 224 cols (7 accs of f32x4 per half-sweep, fully unrolled) and
//   fires the stores in a tight burst. A strip's cache lines open and complete
//   within ~hundreds of cycles instead of the whole pass -> open-line working
//   set per XCD drops ~50x -> L2 can aggregate full 128B lines (theory: the
//   ~5us residual was partial-line eviction write-amp; R5/R12 evidence).
// Pass 1 (max) unchanged: 32x32x16 tiles, waves 0..6.
// 16x16x32 layouts [m89/m91]: C/D col=lane&15, row=4*(lane>>4)+reg;
// A row=lane&15, k=8*(lane>>4)+j (symmetric to verified 32x32 usage).

#define NT 64
#define TDIM 224
#define NTL 7
#define BLK 512

typedef short bf16x8 __attribute__((ext_vector_type(8)));
typedef float f32x16 __attribute__((ext_vector_type(16)));
typedef float f32x4  __attribute__((ext_vector_type(4)));

// f32 -> bf16 round-to-nearest-even
static __device__ inline unsigned short f2bf(float f) {
    unsigned int u = __float_as_uint(f);
    u = (u + 0x7FFFu + ((u >> 16) & 1u)) >> 16;
    return (unsigned short)u;
}

struct __align__(16) SMem {
    unsigned short Rm[TDIM][64];   // 28,672 B, swizzled (rows = y)
    unsigned short Cm[TDIM][64];   // 28,672 B, swizzled (rows = x)  (contiguous with Rm)
    float k1f[37];                 // f32 normalized 1-D gaussian
    float wmax[NTL];
};

__global__ __launch_bounds__(BLK, 4) void heatmap_kernel(const float* __restrict__ x_t,
                                                         float* __restrict__ out) {
    __shared__ SMem s;
    const int tid  = threadIdx.x;
    const int lane = tid & 63;
    const int wv   = tid >> 6;      // 0..7
    const int b    = blockIdx.x;

    // --- (1) zero-fill Rm+Cm with b128 writes: 57,344 B = 3584 x 16 B ---
    {
        uint4 z = {0u, 0u, 0u, 0u};
        uint4* base = (uint4*)s.Rm;
        #pragma unroll
        for (int i = 0; i < 7; ++i) base[tid + BLK * i] = z;
    }
    // --- (2) f32 normalized 1-D gaussian table ---
    if (tid < 37) {
        float sum = 0.0f, mine = 0.0f;
        #pragma unroll
        for (int i = 0; i < 37; ++i) {
            float r = (float)(i - 18);
            float v = expf(-(r * r) * (1.0f / 18.0f));   // sigma=3 -> 2*sigma^2=18
            sum += v;
            if (i == tid) mine = v;
        }
        s.k1f[tid] = mine / sum;
    }
    __syncthreads();

    // --- (3) sparse build: task = (point p, matrix R/C), 4 threads x 9 rows ---
    {
        const int p   = (tid >> 2) & 63;    // point
        const int isC = tid >> 8;           // 0: Rm (rows=y), 1: Cm (rows=x)
        const int j   = tid & 3;            // 9-row slice
        const float2 xy = *(const float2*)(x_t + (size_t)b * 128 + 2 * p);
        // replicates reference exactly
        const bool valid = (xy.x == xy.x) && (xy.y == xy.y);
        const int xp = (int)(xy.x * 2.0f);            // trunc == astype(int32), x>=0
        const int yp = 200 - (int)(xy.y * 2.0f);
        const int xs = min(max(xp - 18, 0), 164);
        const int ys = min(max(yp - 18, 0), 164);
        const int kx = valid ? (min(max(xp + 18, 0), 200) - xs) : 0;   // <= 36
        const int ky = valid ? (min(max(yp + 18, 0), 200) - ys) : 0;
        const int start = isC ? xs : ys;
        const int len   = isC ? kx : ky;
        char* dst = isC ? (char*)s.Cm : (char*)s.Rm;
        #pragma unroll
        for (int i = 0; i < 9; ++i) {
            const int rel = j * 9 + i;                // 0..35
            if (rel < len) {
                const int row = start + rel;          // <= 199
                const int off = (2 * p) ^ ((row & 7) << 4);
                *(unsigned short*)(dst + row * 128 + off) = f2bf(s.k1f[rel]);
            }
        }
    }
    __syncthreads();

    const int swl = (lane & 7) << 4;    // swizzle term

    // --- pass 1: max (unchanged, 32x32x16, waves 0..6) ---
    float gmax = 0.0f;
    if (wv < NTL) {
        bf16x8 A[4];
        const char* ab = (const char*)s.Rm + (wv * 32 + (lane & 31)) * 128;
        #pragma unroll
        for (int m = 0; m < 4; ++m)
            A[m] = *(const bf16x8*)(ab + ((16 * (2 * m + (lane >> 5))) ^ swl));
        for (int tx = 0; tx < NTL; ++tx) {
            const char* bb = (const char*)s.Cm + (tx * 32 + (lane & 31)) * 128;
            f32x16 acc;
            #pragma unroll
            for (int r = 0; r < 16; ++r) acc[r] = 0.0f;
            #pragma unroll
            for (int m = 0; m < 4; ++m) {
                bf16x8 B = *(const bf16x8*)(bb + ((16 * (2 * m + (lane >> 5))) ^ swl));
                acc = __builtin_amdgcn_mfma_f32_32x32x16_bf16(A[m], B, acc, 0, 0, 0);
            }
            #pragma unroll
            for (int r = 0; r < 16; ++r) gmax = fmaxf(gmax, acc[r]);
        }
    }
    #pragma unroll
    for (int off = 32; off > 0; off >>= 1) gmax = fmaxf(gmax, __shfl_xor(gmax, off));
    if (wv < NTL && lane == 0) s.wmax[wv] = gmax;
    __syncthreads();
    float mm = s.wmax[0];
    #pragma unroll
    for (int w = 1; w < NTL; ++w) mm = fmaxf(mm, s.wmax[w]);
    const float scale = 1.0f / (mm + 1e-10f);

    // --- pass 2: 13 strips of 16 rows; 16x16x32 MFMA; burst stores ---
    // All 8 waves: wave w -> strips w and w+8 (w<5). Per strip: A-frags fixed,
    // two half-sweeps of 7 x-tiles each (28 acc VGPR), then 28 stores back-to-
    // back: the strip's lines complete within the burst -> full-line writeback.
    {
        float* ob = out + (size_t)b * (200 * 200);
        for (int sid = wv; sid < 13; sid += 8) {
            const int r0 = 16 * sid;
            bf16x8 Af2[2];
            {
                const char* ab = (const char*)s.Rm + (r0 + (lane & 15)) * 128;
                #pragma unroll
                for (int kk = 0; kk < 2; ++kk)
                    Af2[kk] = *(const bf16x8*)(ab + ((16 * (lane >> 4) + 64 * kk) ^ swl));
            }
            #pragma unroll
            for (int h2 = 0; h2 < 2; ++h2) {
                f32x4 acc2[7];
                #pragma unroll
                for (int t = 0; t < 7; ++t) {
                    acc2[t][0] = 0.0f; acc2[t][1] = 0.0f;
                    acc2[t][2] = 0.0f; acc2[t][3] = 0.0f;
                }
                #pragma unroll
                for (int t = 0; t < 7; ++t) {
                    const int xt = 7 * h2 + t;
                    const char* bb = (const char*)s.Cm + (xt * 16 + (lane & 15)) * 128;
                    #pragma unroll
                    for (int kk = 0; kk < 2; ++kk) {
                        bf16x8 Bf = *(const bf16x8*)(bb + ((16 * (lane >> 4) + 64 * kk) ^ swl));
                        acc2[t] = __builtin_amdgcn_mfma_f32_16x16x32_bf16(Af2[kk], Bf,
                                                                          acc2[t], 0, 0, 0);
                    }
                }
                const int rl = 4 * (lane >> 4);
                #pragma unroll
                for (int j = 0; j < 4; ++j) {
                    const int grow = r0 + rl + j;
                    if (grow < 200) {
                        #pragma unroll
                        for (int t = 0; t < 7; ++t) {
                            const int gcol = (7 * h2 + t) * 16 + (lane & 15);
                            if (gcol < 200)
                                ob[(size_t)grow * 200 + gcol] = acc2[t][j] * scale;
                        }
                    }
                }
            }
        }
    }
}

extern "C" void kernel_launch(void* const* d_in, const int* in_sizes, int n_in,
                              void* d_out, int out_size, void* d_ws, size_t ws_size,
                              hipStream_t stream) {
    const float* x_t = (const float*)d_in[0];
    float* out = (float*)d_out;
    const int B = in_sizes[0] / (NT * 2);   // 512
    heatmap_kernel<<<B, BLK, 0, stream>>>(x_t, out);
}

// Round 14
// 25.525 us; speedup vs baseline: 1.9231x; 1.3506x over previous
//
#include <hip/hip_runtime.h>

// Gaussian-splat heatmap as a per-image MFMA GEMM — R11 with 1024 threads/block
// (single structural change vs R11, 24.26us: 16 waves on ONE image instead of
// 2 co-resident 8-wave images per CU).
//   heat[y][x] = sum_p Rmat[y][p] * CmatT[x][p]   (M=N=200 padded to 224, K=64)
//   Rmat[y][p]  = k1n[y-ys_p] if 0<=y-ys_p<ky_p else 0  (top-left-slice quirk)
//   CmatT[x][p] = k1n[x-xs_p] if 0<=x-xs_p<kx_p else 0
// bf16 LDS rows of 128 B, XOR-swizzled byte ^= ((row&7)<<4) (G4/T2).
// mfma_f32_32x32x16_bf16; A-frag: lane l -> row l&31, k=8*(l>>5)+j;
// C/D: col=lane&31, row=(reg&3)+8*(reg>>2)+4*(lane>>5)   [m74/m101]
//
// Rationale: R11's 2 blocks/CU run near-lockstep; per-image phase wall-time is
// 7 tx/wave and the HBM idles during the ~4-5us build+pass1 prefix. Here each
// image gets 16 waves (wave w -> ty=w>>1, half=w&1; half 0: tx 0..3, half 1:
// tx 4..6) halving every phase, and the 512 blocks run as 2 pipelined rounds
// on 256 CUs: round-2 prefixes overlap round-1 store drain. Store pattern,
// build, swizzle, arithmetic: byte-identical to R11.
// Falsifier: if this regresses (>=26us), 2-image-per-CU concurrency was the
// lever and R11 is the keeper.

#define NT 64
#define TDIM 224
#define NTL 7
#define BLK 1024

typedef short bf16x8 __attribute__((ext_vector_type(8)));
typedef float f32x16 __attribute__((ext_vector_type(16)));

// f32 -> bf16 round-to-nearest-even
static __device__ inline unsigned short f2bf(float f) {
    unsigned int u = __float_as_uint(f);
    u = (u + 0x7FFFu + ((u >> 16) & 1u)) >> 16;
    return (unsigned short)u;
}

struct __align__(16) SMem {
    unsigned short Rm[TDIM][64];   // 28,672 B, swizzled (rows = y)
    unsigned short Cm[TDIM][64];   // 28,672 B, swizzled (rows = x)  (contiguous with Rm)
    float k1f[37];                 // f32 normalized 1-D gaussian
    float wmax[14];
};

__global__ __launch_bounds__(BLK) void heatmap_kernel(const float* __restrict__ x_t,
                                                      float* __restrict__ out) {
    __shared__ SMem s;
    const int tid  = threadIdx.x;
    const int lane = tid & 63;
    const int wv   = tid >> 6;      // 0..15
    const int b    = blockIdx.x;

    // --- (1) zero-fill Rm+Cm with b128 writes: 57,344 B = 3584 x 16 B ---
    {
        uint4 z = {0u, 0u, 0u, 0u};
        uint4* base = (uint4*)s.Rm;
        #pragma unroll
        for (int i = 0; i < 4; ++i) {
            const int idx = tid + BLK * i;
            if (idx < 3584) base[idx] = z;
        }
    }
    // --- (2) f32 normalized 1-D gaussian table ---
    if (tid < 37) {
        float sum = 0.0f, mine = 0.0f;
        #pragma unroll
        for (int i = 0; i < 37; ++i) {
            float r = (float)(i - 18);
            float v = expf(-(r * r) * (1.0f / 18.0f));   // sigma=3 -> 2*sigma^2=18
            sum += v;
            if (i == tid) mine = v;
        }
        s.k1f[tid] = mine / sum;
    }
    __syncthreads();

    // --- (3) sparse build: task = (point p, matrix R/C), 8 threads x 5 rows ---
    {
        const int p   = (tid >> 3) & 63;    // point
        const int isC = tid >> 9;           // 0: Rm (rows=y), 1: Cm (rows=x)
        const int j   = tid & 7;            // 5-row slice
        const float2 xy = *(const float2*)(x_t + (size_t)b * 128 + 2 * p);
        // replicates reference exactly
        const bool valid = (xy.x == xy.x) && (xy.y == xy.y);
        const int xp = (int)(xy.x * 2.0f);            // trunc == astype(int32), x>=0
        const int yp = 200 - (int)(xy.y * 2.0f);
        const int xs = min(max(xp - 18, 0), 164);
        const int ys = min(max(yp - 18, 0), 164);
        const int kx = valid ? (min(max(xp + 18, 0), 200) - xs) : 0;   // <= 36
        const int ky = valid ? (min(max(yp + 18, 0), 200) - ys) : 0;
        const int start = isC ? xs : ys;
        const int len   = isC ? kx : ky;
        char* dst = isC ? (char*)s.Cm : (char*)s.Rm;
        #pragma unroll
        for (int i = 0; i < 5; ++i) {
            const int rel = j * 5 + i;                // 0..39
            if (rel < len) {
                const int row = start + rel;          // <= 199
                const int off = (2 * p) ^ ((row & 7) << 4);
                *(unsigned short*)(dst + row * 128 + off) = f2bf(s.k1f[rel]);
            }
        }
    }
    __syncthreads();

    const int swl  = (lane & 7) << 4;   // swizzle term (rows = t*32+(lane&31))
    const int ty   = wv >> 1;           // 0..7 (ty==7 -> idle waves 14,15)
    const int half = wv & 1;
    const int tx0  = half ? 4 : 0;
    const int tx1  = half ? 7 : 4;

    // --- A fragments for this wave's y-tile ---
    bf16x8 A[4];
    if (ty < NTL) {
        const char* ab = (const char*)s.Rm + (ty * 32 + (lane & 31)) * 128;
        #pragma unroll
        for (int m = 0; m < 4; ++m)
            A[m] = *(const bf16x8*)(ab + ((16 * (2 * m + (lane >> 5))) ^ swl));
    }

    // --- pass 1: max over this wave's tx range ---
    float gmax = 0.0f;
    if (ty < NTL) {
        for (int tx = tx0; tx < tx1; ++tx) {
            const char* bb = (const char*)s.Cm + (tx * 32 + (lane & 31)) * 128;
            f32x16 acc;
            #pragma unroll
            for (int r = 0; r < 16; ++r) acc[r] = 0.0f;
            #pragma unroll
            for (int m = 0; m < 4; ++m) {
                bf16x8 B = *(const bf16x8*)(bb + ((16 * (2 * m + (lane >> 5))) ^ swl));
                acc = __builtin_amdgcn_mfma_f32_32x32x16_bf16(A[m], B, acc, 0, 0, 0);
            }
            #pragma unroll
            for (int r = 0; r < 16; ++r) gmax = fmaxf(gmax, acc[r]);
        }
    }
    #pragma unroll
    for (int off = 32; off > 0; off >>= 1) gmax = fmaxf(gmax, __shfl_xor(gmax, off));
    if (ty < NTL && lane == 0) s.wmax[wv] = gmax;
    __syncthreads();
    float mm = s.wmax[0];
    #pragma unroll
    for (int w = 1; w < 14; ++w) mm = fmaxf(mm, s.wmax[w]);
    const float scale = 1.0f / (mm + 1e-10f);

    // --- pass 2: recompute own tx range, normalize, store (R11 pattern) ---
    if (ty < NTL) {
        float* ob = out + (size_t)b * (200 * 200);
        const int colbase = lane & 31;
        const int rowoff  = ty * 32 + 4 * (lane >> 5);
        for (int tx = tx0; tx < tx1; ++tx) {
            const char* bb = (const char*)s.Cm + (tx * 32 + (lane & 31)) * 128;
            f32x16 acc;
            #pragma unroll
            for (int r = 0; r < 16; ++r) acc[r] = 0.0f;
            #pragma unroll
            for (int m = 0; m < 4; ++m) {
                bf16x8 B = *(const bf16x8*)(bb + ((16 * (2 * m + (lane >> 5))) ^ swl));
                acc = __builtin_amdgcn_mfma_f32_32x32x16_bf16(A[m], B, acc, 0, 0, 0);
            }
            const int gcol = tx * 32 + colbase;
            #pragma unroll
            for (int r = 0; r < 16; ++r) {
                int grow = rowoff + (r & 3) + 8 * (r >> 2);
                if (grow < 200 && gcol < 200)
                    ob[(size_t)grow * 200 + gcol] = acc[r] * scale;
            }
        }
    }
}

extern "C" void kernel_launch(void* const* d_in, const int* in_sizes, int n_in,
                              void* d_out, int out_size, void* d_ws, size_t ws_size,
                              hipStream_t stream) {
    const float* x_t = (const float*)d_in[0];
    float* out = (float*)d_out;
    const int B = in_sizes[0] / (NT * 2);   // 512
    heatmap_kernel<<<B, BLK, 0, stream>>>(x_t, out);
}